// Round 13
// baseline (85.149 us; speedup 1.0000x reference)
//
#include <hip/hip_runtime.h>

#define N_ROWS 14400
#define M_COLS 1600
#define KDIM   256
#define GRID_X 25           // 1600 / 64 col-tiles (exact)
#define GRID_Y 113          // ceil(14400/128) row-tiles
#define NWG    (GRID_X * GRID_Y)   // 2825

// Workspace layout (bytes):
//   probB : [0, 7372800)               14400*256 bf16
//   embB  : [7372800, 8192000)         1600*256 bf16
//   colD  : [8192000, 8249600)         9 x 1600 f32 SOA
//   scores: [8249600, 54534400)        2825*4*2048 fp16 (packed j-major)
#define COLD_OFF   8192000ull
#define SC_OFF     8249600ull
#define WS_NEED    54534400ull

typedef __attribute__((ext_vector_type(8))) short bf16x8;
typedef __attribute__((ext_vector_type(4))) float f32x4;
typedef __attribute__((ext_vector_type(8))) unsigned short u16x8;

__device__ __forceinline__ short f2bf(float x) {
  union { float f; unsigned u; } v; v.f = x;
  unsigned r = v.u + 0x7FFFu + ((v.u >> 16) & 1u);   // RNE to bf16
  return (short)(r >> 16);
}

__device__ __forceinline__ void gload_lds16(const void* g, void* l) {
  __builtin_amdgcn_global_load_lds(
      (const __attribute__((address_space(1))) void*)g,
      (__attribute__((address_space(3))) void*)l, 16, 0, 0);
}

// One WAVE per row; lane handles 4 consecutive floats. Extra blocks (if
// launched) fill the colD SOA table from tbox.
__global__ __launch_bounds__(256) void prep_kernel(
    const float* __restrict__ logits, const float* __restrict__ embs,
    const float* __restrict__ tbox,
    short* __restrict__ probB, short* __restrict__ embB,
    float* __restrict__ colD) {
  if (blockIdx.x >= (N_ROWS + M_COLS) / 4) {
    for (int c = threadIdx.x; c < M_COLS; c += 256) {
      const float4 bb = ((const float4*)tbox)[c];
      colD[0 * M_COLS + c] = fmaf(-0.5f, bb.z, bb.x);   // x1
      colD[1 * M_COLS + c] = fmaf(-0.5f, bb.w, bb.y);   // y1
      colD[2 * M_COLS + c] = fmaf(0.5f, bb.z, bb.x);    // x2
      colD[3 * M_COLS + c] = fmaf(0.5f, bb.w, bb.y);    // y2
      colD[4 * M_COLS + c] = bb.x;                      // cx
      colD[5 * M_COLS + c] = bb.y;                      // cy
      colD[6 * M_COLS + c] = bb.z;                      // w
      colD[7 * M_COLS + c] = bb.w;                      // h
      colD[8 * M_COLS + c] = bb.z * bb.w;               // area
    }
    return;
  }
  const int row = blockIdx.x * 4 + (threadIdx.x >> 6);
  const int lane = threadIdx.x & 63;
  if (row < N_ROWS) {
    const float4 x = ((const float4*)(logits + (size_t)row * KDIM))[lane];
    float s = x.x * x.x + x.y * x.y + x.z * x.z + x.w * x.w;
#pragma unroll
    for (int o = 32; o > 0; o >>= 1) s += __shfl_xor(s, o, 64);
    const float scale = __builtin_amdgcn_rsqf(s);
    short4 o4;
    o4.x = f2bf(x.x * scale); o4.y = f2bf(x.y * scale);
    o4.z = f2bf(x.z * scale); o4.w = f2bf(x.w * scale);
    ((short4*)(probB + (size_t)row * KDIM))[lane] = o4;
  } else {
    const int r = row - N_ROWS;
    const float4 x = ((const float4*)(embs + (size_t)r * KDIM))[lane];
    short4 o4;
    o4.x = f2bf(x.x); o4.y = f2bf(x.y); o4.z = f2bf(x.z); o4.w = f2bf(x.w);
    ((short4*)(embB + (size_t)r * KDIM))[lane] = o4;
  }
}

// ---------- SPLIT PATH: lean GEMM -> packed fp16 scores ----------
// r11's proven K-loop verbatim; epilogue = 32 coalesced short-stores in
// MFMA-native j-major layout. No box staging, no transpose, no epilogue
// barriers -> lean regs -> high occupancy. Normal stores (L3-resident).
__global__ __launch_bounds__(256) void gemm_kernel(
    const short* __restrict__ probB, const short* __restrict__ embB,
    unsigned short* __restrict__ sc) {
  __shared__ short As[128 * 64];    // 16 KB
  __shared__ short Bs[64 * 64];     // 8 KB

  const int t = threadIdx.x;
  const int lane = t & 63;
  const int wid = t >> 6;
  const int wr = wid >> 1;
  const int wc = wid & 1;

  // Bijective XCD swizzle (m204).
  const int orig = blockIdx.x;
  const int xcd = orig & 7;
  const int rem = orig >> 3;
  const int q = NWG >> 3, r = NWG & 7;
  const int wgid = (xcd < r ? xcd * (q + 1) : r * (q + 1) + (xcd - r) * q) + rem;
  const int bx = wgid % GRID_X;
  const int by = wgid / GRID_X;
  const int rowBase = by * 128;
  const int colBase = bx * 64;

  f32x4 acc[4][2];
#pragma unroll
  for (int i = 0; i < 4; ++i)
#pragma unroll
    for (int j = 0; j < 2; ++j) acc[i][j] = (f32x4){0.f, 0.f, 0.f, 0.f};

  const int swz = (lane & 7) ^ (lane >> 3);
  const int rbase = wid * 8 + (lane >> 3);

  for (int kt = 0; kt < 4; ++kt) {
    const int k0 = kt * 64 + swz * 8;
#pragma unroll
    for (int i = 0; i < 4; ++i) {
      int gr = rowBase + i * 32 + rbase;
      if (gr > N_ROWS - 1) gr = N_ROWS - 1;
      gload_lds16(probB + (size_t)gr * KDIM + k0, As + (i * 32 + wid * 8) * 64);
    }
#pragma unroll
    for (int i = 0; i < 2; ++i) {
      const int gc = colBase + i * 32 + rbase;
      gload_lds16(embB + (size_t)gc * KDIM + k0, Bs + (i * 32 + wid * 8) * 64);
    }
    __syncthreads();
#pragma unroll
    for (int kk = 0; kk < 2; ++kk) {
      bf16x8 af[4], bfr[2];
      const int g = kk * 4 + (lane >> 4);
#pragma unroll
      for (int mi = 0; mi < 4; ++mi) {
        const int row = wr * 64 + mi * 16 + (lane & 15);
        af[mi] = *(const bf16x8*)(As + row * 64 + ((g ^ (row & 7)) * 8));
      }
#pragma unroll
      for (int ni = 0; ni < 2; ++ni) {
        const int row = wc * 32 + ni * 16 + (lane & 15);
        bfr[ni] = *(const bf16x8*)(Bs + row * 64 + ((g ^ (row & 7)) * 8));
      }
#pragma unroll
      for (int mi = 0; mi < 4; ++mi)
#pragma unroll
        for (int ni = 0; ni < 2; ++ni)
          acc[mi][ni] = __builtin_amdgcn_mfma_f32_16x16x32_bf16(
              af[mi], bfr[ni], acc[mi][ni], 0, 0, 0);
    }
    __syncthreads();
  }

  // Packed j-major store: idx = ((wgid*4+wid)*2048) + mi*512+ni*256+j*64+lane.
  const size_t sbase = ((size_t)wgid * 4 + wid) * 2048;
#pragma unroll
  for (int mi = 0; mi < 4; ++mi)
#pragma unroll
    for (int ni = 0; ni < 2; ++ni)
#pragma unroll
      for (int j = 0; j < 4; ++j) {
        union { _Float16 h; unsigned short u; } cv;
        cv.h = (_Float16)acc[mi][ni][j];
        sc[sbase + mi * 512 + ni * 256 + j * 64 + lane] = cv.u;
      }
}

// ---------- SPLIT PATH: streaming epilogue ----------
// One thread = 8 consecutive cols of one row. Pure streaming: ushort8 score
// load (packed layout inverse), SOA col loads (L2-hit), 32 VALU/output,
// NT float4 stores.
__global__ __launch_bounds__(256) void epi_kernel(
    const unsigned short* __restrict__ sc, const float* __restrict__ pbox,
    const float* __restrict__ colD, float* __restrict__ out) {
  const int tid = blockIdx.x * 256 + threadIdx.x;   // 0..2879999 exact
  const int row = tid / 200;
  const int c0 = (tid - row * 200) * 8;

  // Inverse of the GEMM packed layout.
  const int by = row >> 7, ry = row & 127;
  const int wr = ry >> 6, mi = (ry >> 4) & 3, qq = (ry >> 2) & 3, j = ry & 3;
  const int bx = c0 >> 6, wc = (c0 >> 5) & 1, ni = (c0 >> 4) & 1, l0 = c0 & 15;
  const int lane = qq * 16 + l0;
  const int wid = wr * 2 + wc;
  const size_t sidx = ((size_t)(by * GRID_X + bx) * 4 + wid) * 2048 +
                      mi * 512 + ni * 256 + j * 64 + lane;
  const u16x8 sv = *(const u16x8*)(sc + sidx);

  const float4 rb = ((const float4*)pbox)[row];
  const float rx1 = fmaf(-0.5f, rb.z, rb.x);
  const float ry1 = fmaf(-0.5f, rb.w, rb.y);
  const float rx2 = fmaf(0.5f, rb.z, rb.x);
  const float ry2 = fmaf(0.5f, rb.w, rb.y);
  const float ra = rb.z * rb.w;
  const float LOG2E = 1.44269504f;

#pragma unroll
  for (int h = 0; h < 2; ++h) {
    const int ch = c0 + h * 4;
    const f32x4 X1 = *(const f32x4*)(colD + 0 * M_COLS + ch);
    const f32x4 Y1 = *(const f32x4*)(colD + 1 * M_COLS + ch);
    const f32x4 X2 = *(const f32x4*)(colD + 2 * M_COLS + ch);
    const f32x4 Y2 = *(const f32x4*)(colD + 3 * M_COLS + ch);
    const f32x4 CX = *(const f32x4*)(colD + 4 * M_COLS + ch);
    const f32x4 CY = *(const f32x4*)(colD + 5 * M_COLS + ch);
    const f32x4 CW = *(const f32x4*)(colD + 6 * M_COLS + ch);
    const f32x4 CH = *(const f32x4*)(colD + 7 * M_COLS + ch);
    const f32x4 CA = *(const f32x4*)(colD + 8 * M_COLS + ch);
    f32x4 res;
#pragma unroll
    for (int k = 0; k < 4; ++k) {
      union { unsigned short u; _Float16 hh; } cv;
      cv.u = sv[h * 4 + k];
      const float cc = fmaxf((float)cv.hh, 0.0f);
      const float l1 = fabsf(rb.x - CX[k]) + fabsf(rb.y - CY[k]) +
                       fabsf(rb.z - CW[k]) + fabsf(rb.w - CH[k]);
      const float iwx = fminf(rx2, X2[k]) - fmaxf(rx1, X1[k]);
      const float iwy = fminf(ry2, Y2[k]) - fmaxf(ry1, Y1[k]);
      const float iw = fmaxf(iwx, 0.f);
      const float ih = fmaxf(iwy, 0.f);
      const float inter = iw * ih;
      const float uni = ra + CA[k] - inter;
      const float ex = (rb.z + CW[k]) - iwx;
      const float ey = (rb.w + CH[k]) - iwy;
      const float earea = ex * ey;
      const float num = fmaf(uni, uni, inter * earea);
      const float Cv = fmaf(-num, __builtin_amdgcn_rcpf(uni * earea),
                            l1 + cc + 1.0f);
      res[k] = __builtin_amdgcn_rcpf(
          1.0f + __builtin_amdgcn_exp2f(-LOG2E * Cv));
    }
    __builtin_nontemporal_store(res, (f32x4*)(out + (size_t)row * M_COLS + ch));
  }
}

// ---------- FALLBACK: r11 fused kernel (48.1 us), used if ws too small ----
__global__ __launch_bounds__(256) void cost_kernel(
    const short* __restrict__ probB, const short* __restrict__ embB,
    const float* __restrict__ pbox, const float* __restrict__ tbox,
    float* __restrict__ out) {
  __shared__ short As[128 * 64];
  __shared__ short Bs[64 * 64];
  __shared__ f32x4 rowcc[128], rowxy[128];
  __shared__ f32x4 colcc[64],  colxy[64];
  float* const tbuf = (float*)As;

  const int t = threadIdx.x;
  const int lane = t & 63;
  const int wid = t >> 6;
  const int wr = wid >> 1;
  const int wc = wid & 1;

  const int orig = blockIdx.x;
  const int xcd = orig & 7;
  const int rem = orig >> 3;
  const int q = NWG >> 3, r = NWG & 7;
  const int wgid = (xcd < r ? xcd * (q + 1) : r * (q + 1) + (xcd - r) * q) + rem;
  const int bx = wgid % GRID_X;
  const int by = wgid / GRID_X;
  const int rowBase = by * 128;
  const int colBase = bx * 64;

  if (t < 128) {
    const int idx = rowBase + t;
    const int ci = idx < N_ROWS ? idx : N_ROWS - 1;
    const float4 bb = ((const float4*)pbox)[ci];
    rowcc[t] = (f32x4){bb.x, bb.y, bb.z, bb.w};
    rowxy[t] = (f32x4){fmaf(-0.5f, bb.z, bb.x), fmaf(-0.5f, bb.w, bb.y),
                       fmaf(0.5f, bb.z, bb.x), fmaf(0.5f, bb.w, bb.y)};
  } else if (t < 192) {
    const int c = t - 128;
    const float4 bb = ((const float4*)tbox)[colBase + c];
    colcc[c] = (f32x4){bb.x, bb.y, bb.z, bb.w};
    colxy[c] = (f32x4){fmaf(-0.5f, bb.z, bb.x), fmaf(-0.5f, bb.w, bb.y),
                       fmaf(0.5f, bb.z, bb.x), fmaf(0.5f, bb.w, bb.y)};
  }

  f32x4 acc[4][2];
#pragma unroll
  for (int i = 0; i < 4; ++i)
#pragma unroll
    for (int j = 0; j < 2; ++j) acc[i][j] = (f32x4){0.f, 0.f, 0.f, 0.f};

  const int swz = (lane & 7) ^ (lane >> 3);
  const int rbase = wid * 8 + (lane >> 3);

  for (int kt = 0; kt < 4; ++kt) {
    const int k0 = kt * 64 + swz * 8;
#pragma unroll
    for (int i = 0; i < 4; ++i) {
      int gr = rowBase + i * 32 + rbase;
      if (gr > N_ROWS - 1) gr = N_ROWS - 1;
      gload_lds16(probB + (size_t)gr * KDIM + k0, As + (i * 32 + wid * 8) * 64);
    }
#pragma unroll
    for (int i = 0; i < 2; ++i) {
      const int gc = colBase + i * 32 + rbase;
      gload_lds16(embB + (size_t)gc * KDIM + k0, Bs + (i * 32 + wid * 8) * 64);
    }
    __syncthreads();
#pragma unroll
    for (int kk = 0; kk < 2; ++kk) {
      bf16x8 af[4], bfr[2];
      const int g = kk * 4 + (lane >> 4);
#pragma unroll
      for (int mi = 0; mi < 4; ++mi) {
        const int row = wr * 64 + mi * 16 + (lane & 15);
        af[mi] = *(const bf16x8*)(As + row * 64 + ((g ^ (row & 7)) * 8));
      }
#pragma unroll
      for (int ni = 0; ni < 2; ++ni) {
        const int row = wc * 32 + ni * 16 + (lane & 15);
        bfr[ni] = *(const bf16x8*)(Bs + row * 64 + ((g ^ (row & 7)) * 8));
      }
#pragma unroll
      for (int mi = 0; mi < 4; ++mi)
#pragma unroll
        for (int ni = 0; ni < 2; ++ni)
          acc[mi][ni] = __builtin_amdgcn_mfma_f32_16x16x32_bf16(
              af[mi], bfr[ni], acc[mi][ni], 0, 0, 0);
    }
    __syncthreads();
  }

  const float LOG2E = 1.44269504f;
  const int jr = (lane >> 4) * 4;
  const int lc = lane & 15;
  f32x4 c0v[2], c1v[2];
  float cav[2];
#pragma unroll
  for (int ni = 0; ni < 2; ++ni) {
    const int cloc = wc * 32 + ni * 16 + lc;
    c0v[ni] = colcc[cloc];
    c1v[ni] = colxy[cloc];
    cav[ni] = c0v[ni][2] * c0v[ni][3];
  }

#pragma unroll
  for (int mi = 0; mi < 4; ++mi) {
    float* const tb = tbuf + (mi & 1) * 2176;
#pragma unroll
    for (int j = 0; j < 4; ++j) {
      const int rloc = wr * 64 + mi * 16 + jr + j;
      const f32x4 r0 = rowcc[rloc];
      const f32x4 r1 = rowxy[rloc];
      const float ra = r0[2] * r0[3];
#pragma unroll
      for (int ni = 0; ni < 2; ++ni) {
        const f32x4 c0 = c0v[ni], c1 = c1v[ni];
        const float cc = fmaxf(acc[mi][ni][j], 0.0f);
        const float l1 = fabsf(r0[0] - c0[0]) + fabsf(r0[1] - c0[1]) +
                         fabsf(r0[2] - c0[2]) + fabsf(r0[3] - c0[3]);
        const float iwx = fminf(r1[2], c1[2]) - fmaxf(r1[0], c1[0]);
        const float iwy = fminf(r1[3], c1[3]) - fmaxf(r1[1], c1[1]);
        const float iw = fmaxf(iwx, 0.f);
        const float ih = fmaxf(iwy, 0.f);
        const float inter = iw * ih;
        const float uni = ra + cav[ni] - inter;
        const float ex = (r0[2] + c0[2]) - iwx;
        const float ey = (r0[3] + c0[3]) - iwy;
        const float earea = ex * ey;
        const float num = fmaf(uni, uni, inter * earea);
        const float Cv = fmaf(-num, __builtin_amdgcn_rcpf(uni * earea),
                              l1 + cc + 1.0f);
        const float sg = __builtin_amdgcn_rcpf(
            1.0f + __builtin_amdgcn_exp2f(-LOG2E * Cv));
        tb[(wr * 16 + jr + j) * 68 + wc * 32 + ni * 16 + lc] = sg;
      }
    }
    asm volatile("s_waitcnt lgkmcnt(0)" ::: "memory");
    __builtin_amdgcn_s_barrier();
#pragma unroll
    for (int rr = 0; rr < 2; ++rr) {
      const int rch = rr * 16 + (t >> 4);
      const int c4 = (t & 15) * 4;
      const f32x4 v = *(const f32x4*)(tb + rch * 68 + c4);
      const int grow = rowBase + ((rch < 16) ? (mi * 16 + rch)
                                             : (64 + mi * 16 + (rch - 16)));
      if (grow < N_ROWS)
        __builtin_nontemporal_store(
            v, (f32x4*)(out + (size_t)grow * M_COLS + colBase + c4));
    }
  }
}

extern "C" void kernel_launch(void* const* d_in, const int* in_sizes, int n_in,
                              void* d_out, int out_size, void* d_ws, size_t ws_size,
                              hipStream_t stream) {
  const float* logits = (const float*)d_in[0];   // [16,900,256]
  const float* pbox   = (const float*)d_in[1];   // [16,900,4]
  const float* embs   = (const float*)d_in[2];   // [1600,256]
  const float* tbox   = (const float*)d_in[3];   // [1600,4]
  float* out = (float*)d_out;                    // [16,900,1600]

  short* probB = (short*)d_ws;                         // 14400*256 bf16
  short* embB  = probB + (size_t)N_ROWS * KDIM;        // 1600*256 bf16
  float* colD  = (float*)((char*)d_ws + COLD_OFF);     // 9 x 1600 f32
  unsigned short* sc = (unsigned short*)((char*)d_ws + SC_OFF);

  if (ws_size >= WS_NEED) {
    prep_kernel<<<(N_ROWS + M_COLS) / 4 + 1, 256, 0, stream>>>(
        logits, embs, tbox, probB, embB, colD);
    gemm_kernel<<<NWG, 256, 0, stream>>>(probB, embB, sc);
    epi_kernel<<<(N_ROWS * M_COLS) / (8 * 256), 256, 0, stream>>>(
        sc, pbox, colD, out);
  } else {
    prep_kernel<<<(N_ROWS + M_COLS) / 4, 256, 0, stream>>>(
        logits, embs, tbox, probB, embB, colD);
    cost_kernel<<<NWG, 256, 0, stream>>>(probB, embB, pbox, tbox, out);
  }
}

// Round 14
// 47.479 us; speedup vs baseline: 1.7934x; 1.7934x over previous
//
#include <hip/hip_runtime.h>

#define N_ROWS 14400
#define M_COLS 1600
#define KDIM   256
#define GRID_X 25           // 1600 / 64  (exact)
#define GRID_Y 225          // 14400 / 64 (exact)
#define NWG    (GRID_X * GRID_Y)   // 5625

typedef __attribute__((ext_vector_type(8))) short bf16x8;
typedef __attribute__((ext_vector_type(4))) float f32x4;

__device__ __forceinline__ short f2bf(float x) {
  union { float f; unsigned u; } v; v.f = x;
  unsigned r = v.u + 0x7FFFu + ((v.u >> 16) & 1u);   // RNE to bf16
  return (short)(r >> 16);
}

__device__ __forceinline__ void gload_lds16(const void* g, void* l) {
  __builtin_amdgcn_global_load_lds(
      (const __attribute__((address_space(1))) void*)g,
      (__attribute__((address_space(3))) void*)l, 16, 0, 0);
}

// One WAVE per row; lane handles 4 consecutive floats (float4 in, short4 out).
__global__ __launch_bounds__(256) void prep_kernel(
    const float* __restrict__ logits, const float* __restrict__ embs,
    short* __restrict__ probB, short* __restrict__ embB) {
  const int row = blockIdx.x * 4 + (threadIdx.x >> 6);
  const int lane = threadIdx.x & 63;
  if (row < N_ROWS) {
    const float4 x = ((const float4*)(logits + (size_t)row * KDIM))[lane];
    float s = x.x * x.x + x.y * x.y + x.z * x.z + x.w * x.w;
#pragma unroll
    for (int o = 32; o > 0; o >>= 1) s += __shfl_xor(s, o, 64);
    const float scale = __builtin_amdgcn_rsqf(s);
    short4 o4;
    o4.x = f2bf(x.x * scale); o4.y = f2bf(x.y * scale);
    o4.z = f2bf(x.z * scale); o4.w = f2bf(x.w * scale);
    ((short4*)(probB + (size_t)row * KDIM))[lane] = o4;
  } else {
    const int r = row - N_ROWS;   // grid sized exactly, no overflow
    const float4 x = ((const float4*)(embs + (size_t)r * KDIM))[lane];
    short4 o4;
    o4.x = f2bf(x.x); o4.y = f2bf(x.y); o4.z = f2bf(x.z); o4.w = f2bf(x.w);
    ((short4*)(embB + (size_t)r * KDIM))[lane] = o4;
  }
}

// 64x64 tile GEMM (bf16 MFMA) + fused bbox-L1 + GIoU + sigmoid epilogue.
// r14 = r11's structure at finer geometry:
// - 4 waves of 32x32 -> acc[2][2] = 16 AGPR (was 32). Target: total VGPR
//   <= ~102 -> 5 waves/SIMD (r11 was pinned at 4 by 96+32). No launch
//   clamp (r2/r4/r10: forced VGPR<=64 always lost ~10us).
// - 14400=64*225, 1600=64*25 exact: ZERO clamps/guards anywhere.
// - LDS 20 KB. XOR-swizzled GEMM tiles (r11 scheme, 128-B rows) -> 0 bank
//   conflicts.
// - Epilogue: 2 passes; per-wr 16x68 tbuf overlay on dead As; lgkm-only
//   barriers (3 total); 256-B-coalesced dwordx4 NT stores (never drained).
// - Bijective XCD swizzle (FETCH ~7 MB, inputs L2-resident).
__global__ __launch_bounds__(256) void cost_kernel(
    const short* __restrict__ probB, const short* __restrict__ embB,
    const float* __restrict__ pbox, const float* __restrict__ tbox,
    float* __restrict__ out) {
  __shared__ short As[64 * 64];     // 8 KB; tbuf overlays in epilogue
  __shared__ short Bs[64 * 64];     // 8 KB
  __shared__ f32x4 rowcc[64], rowxy[64];   // 2 KB
  __shared__ f32x4 colcc[64], colxy[64];   // 2 KB

  const int t = threadIdx.x;
  const int lane = t & 63;
  const int wid = t >> 6;
  const int wr = wid >> 1;          // wave row 0..1 (32-row band)
  const int wc = wid & 1;           // wave col 0..1 (32-col band)

  // Bijective XCD swizzle (m204): 8 XCDs, NWG=5625 (q=703, r=1).
  const int orig = blockIdx.x;
  const int xcd = orig & 7;
  const int rem = orig >> 3;
  const int q = NWG >> 3, r = NWG & 7;
  const int wgid = (xcd < r ? xcd * (q + 1) : r * (q + 1) + (xcd - r) * q) + rem;
  const int bx = wgid % GRID_X;
  const int by = wgid / GRID_X;
  const int rowBase = by * 64;      // N (pred): always in-range (225*64)
  const int colBase = bx * 64;      // M (tgt):  always in-range (25*64)

  // Stage per-tile box data (no clamps: exact tiling).
  if (t < 64) {
    const float4 bb = ((const float4*)pbox)[rowBase + t];
    rowcc[t] = (f32x4){bb.x, bb.y, bb.z, bb.w};
    rowxy[t] = (f32x4){fmaf(-0.5f, bb.z, bb.x), fmaf(-0.5f, bb.w, bb.y),
                       fmaf(0.5f, bb.z, bb.x), fmaf(0.5f, bb.w, bb.y)};
  } else if (t < 128) {
    const int c = t - 64;
    const float4 bb = ((const float4*)tbox)[colBase + c];
    colcc[c] = (f32x4){bb.x, bb.y, bb.z, bb.w};
    colxy[c] = (f32x4){fmaf(-0.5f, bb.z, bb.x), fmaf(-0.5f, bb.w, bb.y),
                       fmaf(0.5f, bb.z, bb.x), fmaf(0.5f, bb.w, bb.y)};
  }

  f32x4 acc[2][2];
#pragma unroll
  for (int i = 0; i < 2; ++i)
#pragma unroll
    for (int j = 0; j < 2; ++j) acc[i][j] = (f32x4){0.f, 0.f, 0.f, 0.f};

  // Pre-swizzled source granule (r11 scheme, 128-B rows): lane l stages
  // granule (l&7)^(l>>3); read slot g^(row&7) sees linear data.
  const int swz = (lane & 7) ^ (lane >> 3);
  const int rbase = wid * 8 + (lane >> 3);   // staging row within 32-row group

  // K-loop: 4 tiles of BK=64.
  for (int kt = 0; kt < 4; ++kt) {
    const int k0 = kt * 64 + swz * 8;
#pragma unroll
    for (int i = 0; i < 2; ++i) {            // A: 64 rows
      const int gr = rowBase + i * 32 + rbase;
      gload_lds16(probB + (size_t)gr * KDIM + k0, As + (i * 32 + wid * 8) * 64);
    }
#pragma unroll
    for (int i = 0; i < 2; ++i) {            // B: 64 rows (cols)
      const int gc = colBase + i * 32 + rbase;
      gload_lds16(embB + (size_t)gc * KDIM + k0, Bs + (i * 32 + wid * 8) * 64);
    }
    __syncthreads();
#pragma unroll
    for (int kk = 0; kk < 2; ++kk) {
      bf16x8 af[2], bfr[2];
      const int g = kk * 4 + (lane >> 4);    // 16B granule index 0..7
#pragma unroll
      for (int mi = 0; mi < 2; ++mi) {
        const int row = wr * 32 + mi * 16 + (lane & 15);
        af[mi] = *(const bf16x8*)(As + row * 64 + ((g ^ (row & 7)) * 8));
      }
#pragma unroll
      for (int ni = 0; ni < 2; ++ni) {
        const int row = wc * 32 + ni * 16 + (lane & 15);
        bfr[ni] = *(const bf16x8*)(Bs + row * 64 + ((g ^ (row & 7)) * 8));
      }
#pragma unroll
      for (int mi = 0; mi < 2; ++mi)
#pragma unroll
        for (int ni = 0; ni < 2; ++ni)
          acc[mi][ni] = __builtin_amdgcn_mfma_f32_16x16x32_bf16(
              af[mi], bfr[ni], acc[mi][ni], 0, 0, 0);
    }
    __syncthreads();   // last one also protects the tbuf overlay
  }

  // Fused epilogue, 2 passes. Pass mi: each wave writes its 16-row chunk
  // into per-wr tbuf (16x68, 2-way banks) -> lgkm barrier -> all threads
  // read 2 f32x4 and NT-store 256-B coalesced lines -> barrier (pass 0).
  const float LOG2E = 1.44269504f;
  const int jr = (lane >> 4) * 4;
  const int lc = lane & 15;
  float* const tb = (float*)As + wr * 1088;      // this wave's 16x68 buffer
  f32x4 c0v[2], c1v[2];
  float cav[2];
#pragma unroll
  for (int ni = 0; ni < 2; ++ni) {
    const int cloc = wc * 32 + ni * 16 + lc;
    c0v[ni] = colcc[cloc];
    c1v[ni] = colxy[cloc];
    cav[ni] = c0v[ni][2] * c0v[ni][3];
  }

#pragma unroll
  for (int mi = 0; mi < 2; ++mi) {
#pragma unroll
    for (int j = 0; j < 4; ++j) {
      const int rloc = wr * 32 + mi * 16 + jr + j;
      const f32x4 r0 = rowcc[rloc];
      const f32x4 r1 = rowxy[rloc];
      const float ra = r0[2] * r0[3];
#pragma unroll
      for (int ni = 0; ni < 2; ++ni) {
        const f32x4 c0 = c0v[ni], c1 = c1v[ni];
        const float cc = fmaxf(acc[mi][ni][j], 0.0f);
        const float l1 = fabsf(r0[0] - c0[0]) + fabsf(r0[1] - c0[1]) +
                         fabsf(r0[2] - c0[2]) + fabsf(r0[3] - c0[3]);
        const float iwx = fminf(r1[2], c1[2]) - fmaxf(r1[0], c1[0]);
        const float iwy = fminf(r1[3], c1[3]) - fmaxf(r1[1], c1[1]);
        const float iw = fmaxf(iwx, 0.f);
        const float ih = fmaxf(iwy, 0.f);
        const float inter = iw * ih;
        const float uni = ra + cav[ni] - inter;
        const float ex = (r0[2] + c0[2]) - iwx;
        const float ey = (r0[3] + c0[3]) - iwy;
        const float earea = ex * ey;
        const float num = fmaf(uni, uni, inter * earea);
        const float Cv = fmaf(-num, __builtin_amdgcn_rcpf(uni * earea),
                              l1 + cc + 1.0f);
        const float sg = __builtin_amdgcn_rcpf(
            1.0f + __builtin_amdgcn_exp2f(-LOG2E * Cv));
        tb[(jr + j) * 68 + wc * 32 + ni * 16 + lc] = sg;
      }
    }
    // lgkm-only block barrier: LDS writes visible, NT stores keep streaming.
    asm volatile("s_waitcnt lgkmcnt(0)" ::: "memory");
    __builtin_amdgcn_s_barrier();
    // Readback: thread t covers row t>>4 (of 16), 16-B col-group t&15,
    // from BOTH wr-buffers (global rows mi*16+r and 32+mi*16+r).
    {
      const int rch = t >> 4;                // 0..15
      const int c4 = (t & 15) * 4;           // 0..60
      const f32x4 v0 = *(const f32x4*)((float*)As + rch * 68 + c4);
      const f32x4 v1 = *(const f32x4*)((float*)As + 1088 + rch * 68 + c4);
      float* const dst = out + (size_t)(rowBase + mi * 16 + rch) * M_COLS
                         + colBase + c4;
      __builtin_nontemporal_store(v0, (f32x4*)dst);
      __builtin_nontemporal_store(v1, (f32x4*)(dst + 32 * M_COLS));
    }
    if (mi == 0) {   // protect tbuf before pass 1 overwrites it
      asm volatile("s_waitcnt lgkmcnt(0)" ::: "memory");
      __builtin_amdgcn_s_barrier();
    }
  }
}

extern "C" void kernel_launch(void* const* d_in, const int* in_sizes, int n_in,
                              void* d_out, int out_size, void* d_ws, size_t ws_size,
                              hipStream_t stream) {
  const float* logits = (const float*)d_in[0];   // [16,900,256]
  const float* pbox   = (const float*)d_in[1];   // [16,900,4]
  const float* embs   = (const float*)d_in[2];   // [1600,256]
  const float* tbox   = (const float*)d_in[3];   // [1600,4]
  float* out = (float*)d_out;                    // [16,900,1600]

  short* probB = (short*)d_ws;                         // 14400*256 bf16
  short* embB  = probB + (size_t)N_ROWS * KDIM;        // 1600*256 bf16

  prep_kernel<<<(N_ROWS + M_COLS) / 4, 256, 0, stream>>>(logits, embs, probB, embB);

  cost_kernel<<<NWG, 256, 0, stream>>>(probB, embB, pbox, tbox, out);
}